// Round 3
// baseline (7885.632 us; speedup 1.0000x reference)
//
#include <hip/hip_runtime.h>

#define L_DIM 16
#define N_DIM 200000
#define M_DIM 100000
#define F_DIM 7
#define H_DIM 64
#define BT 512   // threads in step kernel: 64 cols x 8 waves, 8 rows/thread

// broadcast lane value across wave via v_readlane (VALU; lane may be dynamic-uniform)
__device__ __forceinline__ float bcast(float v, int lane) {
    return __int_as_float(__builtin_amdgcn_readlane(__float_as_int(v), lane));
}

// ---------------------------------------------------------------------------
// u = tanh(contents_l @ Wu.T + bu)  for all N rows -> out (N,64)
// ---------------------------------------------------------------------------
__global__ __launch_bounds__(256) void u_kernel(const float* __restrict__ contents_l,
                                                const float* __restrict__ Wu,
                                                const float* __restrict__ bu,
                                                float* __restrict__ out) {
    __shared__ float sWu[H_DIM * F_DIM];
    __shared__ float sbu[H_DIM];
    int t = threadIdx.x;
    for (int idx = t; idx < H_DIM * F_DIM; idx += 256) sWu[idx] = Wu[idx];
    if (t < H_DIM) sbu[t] = bu[t];
    __syncthreads();

    int gid = blockIdx.x * 256 + t;
    int i = gid >> 6;
    int h = gid & 63;
    if (i >= N_DIM) return;
    const float* c = contents_l + (size_t)i * F_DIM;
    float acc = sbu[h];
#pragma unroll
    for (int f = 0; f < F_DIM; ++f) acc = fmaf(c[f], sWu[h * F_DIM + f], acc);
    out[(size_t)i * H_DIM + h] = tanhf(acc);
}

// ---------------------------------------------------------------------------
// Interleaved weight prep (same layouts as R2):
//  Wri[(k*64+c)*4+q] = (q<3) ? Wr[(q*64+c)*192 + k] : 0      (192*64*4)
//  Whi[(k4*64+c)*4+q] = Wh[c*192 + 4*k4+q]                    (48*64*4)
//  Wzi[(k*64+c)*4+q] = Wz[(q*64+c)*256 + k]                   (256*64*4)
// ---------------------------------------------------------------------------
__global__ void prep_weights(const float* __restrict__ Wr, const float* __restrict__ Wh,
                             const float* __restrict__ Wz,
                             float* __restrict__ Wri, float* __restrict__ Whi,
                             float* __restrict__ Wzi) {
    const int NWri = 192 * 64 * 4, NWhi = 48 * 64 * 4, NWzi = 256 * 64 * 4;
    int idx = blockIdx.x * 256 + threadIdx.x;
    if (idx < NWri) {
        int q = idx & 3, c = (idx >> 2) & 63, k = idx >> 8;
        Wri[idx] = (q < 3) ? Wr[(q * 64 + c) * 192 + k] : 0.f;
    } else if (idx < NWri + NWhi) {
        int m = idx - NWri;
        int q = m & 3, c = (m >> 2) & 63, k4 = m >> 8;
        Whi[m] = Wh[c * 192 + 4 * k4 + q];
    } else if (idx < NWri + NWhi + NWzi) {
        int m = idx - NWri - NWhi;
        int q = m & 3, c = (m >> 2) & 63, k = m >> 8;
        Wzi[m] = Wz[(q * 64 + c) * 256 + k];
    }
}

// ---------------------------------------------------------------------------
// One scan step. NO LDS, NO barriers. Wave rg owns rows row0..row0+7; lane c
// owns output column c. Activation broadcast via v_readlane from the lane
// that owns that column. Weights stream from L2 (coalesced float4 per lane).
// ---------------------------------------------------------------------------
__global__ __launch_bounds__(BT, 4) void step_kernel(
    const float* __restrict__ embP,
    float* __restrict__ embC,
    const int* __restrict__ chl,
    const float4* __restrict__ WriV, const float* __restrict__ br,
    const float4* __restrict__ WhiV, const float* __restrict__ bh,
    const float4* __restrict__ WziV, const float* __restrict__ bz)
{
    const int t = threadIdx.x;
    const int c = t & 63;
    const int rg = t >> 6;                    // 0..7
    const int row0 = blockIdx.x * 64 + rg * 8;

    // ---- gather: this wave's 8 rows, own column ----
    float hl[8], hr[8], uu[8];
#pragma unroll
    for (int j = 0; j < 8; ++j) {
        int i = row0 + j;
        if (i < M_DIM) {
            int iL = chl[2 * i], iR = chl[2 * i + 1];
            hl[j] = embP[(size_t)iL * 64 + c];
            hr[j] = embP[(size_t)iR * 64 + c];
            uu[j] = embC[(size_t)i * 64 + c];
        } else { hl[j] = 0.f; hr[j] = 0.f; uu[j] = 0.f; }
    }

    // ---- P1a: a0..a2 = hhu @ Wr.T (3 r-gate outputs per lane) ----
    float a0[8], a1[8], a2[8];
#pragma unroll
    for (int j = 0; j < 8; ++j) { a0[j] = 0.f; a1[j] = 0.f; a2[j] = 0.f; }

#pragma unroll 4
    for (int k = 0; k < 64; ++k) {
        float4 w = WriV[k * 64 + c];
#pragma unroll
        for (int j = 0; j < 8; ++j) {
            float s = bcast(hl[j], k);
            a0[j] = fmaf(s, w.x, a0[j]);
            a1[j] = fmaf(s, w.y, a1[j]);
            a2[j] = fmaf(s, w.z, a2[j]);
        }
    }
#pragma unroll 4
    for (int k = 0; k < 64; ++k) {
        float4 w = WriV[(64 + k) * 64 + c];
#pragma unroll
        for (int j = 0; j < 8; ++j) {
            float s = bcast(hr[j], k);
            a0[j] = fmaf(s, w.x, a0[j]);
            a1[j] = fmaf(s, w.y, a1[j]);
            a2[j] = fmaf(s, w.z, a2[j]);
        }
    }
#pragma unroll 4
    for (int k = 0; k < 64; ++k) {
        float4 w = WriV[(128 + k) * 64 + c];
#pragma unroll
        for (int j = 0; j < 8; ++j) {
            float s = bcast(uu[j], k);
            a0[j] = fmaf(s, w.x, a0[j]);
            a1[j] = fmaf(s, w.y, a1[j]);
            a2[j] = fmaf(s, w.z, a2[j]);
        }
    }

    // ---- r = sigmoid(a + br); rh = r * hhu  (overwrite a0..a2 in place) ----
    {
        float b0 = br[c], b1 = br[64 + c], b2 = br[128 + c];
#pragma unroll
        for (int j = 0; j < 8; ++j) {
            a0[j] = hl[j] / (1.f + expf(-(a0[j] + b0)));
            a1[j] = hr[j] / (1.f + expf(-(a1[j] + b1)));
            a2[j] = uu[j] / (1.f + expf(-(a2[j] + b2)));
        }
    }

    // ---- P1b: az = z-partial over hhu columns (Wz cols 64..255) ----
    float az0[8], az1[8], az2[8], az3[8];
#pragma unroll
    for (int j = 0; j < 8; ++j) { az0[j] = 0.f; az1[j] = 0.f; az2[j] = 0.f; az3[j] = 0.f; }

#pragma unroll 4
    for (int k = 0; k < 64; ++k) {
        float4 w = WziV[(64 + k) * 64 + c];
#pragma unroll
        for (int j = 0; j < 8; ++j) {
            float s = bcast(hl[j], k);
            az0[j] = fmaf(s, w.x, az0[j]);
            az1[j] = fmaf(s, w.y, az1[j]);
            az2[j] = fmaf(s, w.z, az2[j]);
            az3[j] = fmaf(s, w.w, az3[j]);
        }
    }
#pragma unroll 4
    for (int k = 0; k < 64; ++k) {
        float4 w = WziV[(128 + k) * 64 + c];
#pragma unroll
        for (int j = 0; j < 8; ++j) {
            float s = bcast(hr[j], k);
            az0[j] = fmaf(s, w.x, az0[j]);
            az1[j] = fmaf(s, w.y, az1[j]);
            az2[j] = fmaf(s, w.z, az2[j]);
            az3[j] = fmaf(s, w.w, az3[j]);
        }
    }
#pragma unroll 4
    for (int k = 0; k < 64; ++k) {
        float4 w = WziV[(192 + k) * 64 + c];
#pragma unroll
        for (int j = 0; j < 8; ++j) {
            float s = bcast(uu[j], k);
            az0[j] = fmaf(s, w.x, az0[j]);
            az1[j] = fmaf(s, w.y, az1[j]);
            az2[j] = fmaf(s, w.z, az2[j]);
            az3[j] = fmaf(s, w.w, az3[j]);
        }
    }

    // ---- P2: hH = tanh(rh @ Wh.T + bh)  (rh lives in a0..a2) ----
    float hH[8];
#pragma unroll
    for (int j = 0; j < 8; ++j) hH[j] = 0.f;

#pragma unroll 4
    for (int k4 = 0; k4 < 16; ++k4) {
        float4 w = WhiV[k4 * 64 + c];
#pragma unroll
        for (int j = 0; j < 8; ++j) {
            hH[j] = fmaf(bcast(a0[j], 4 * k4 + 0), w.x, hH[j]);
            hH[j] = fmaf(bcast(a0[j], 4 * k4 + 1), w.y, hH[j]);
            hH[j] = fmaf(bcast(a0[j], 4 * k4 + 2), w.z, hH[j]);
            hH[j] = fmaf(bcast(a0[j], 4 * k4 + 3), w.w, hH[j]);
        }
    }
#pragma unroll 4
    for (int k4 = 0; k4 < 16; ++k4) {
        float4 w = WhiV[(16 + k4) * 64 + c];
#pragma unroll
        for (int j = 0; j < 8; ++j) {
            hH[j] = fmaf(bcast(a1[j], 4 * k4 + 0), w.x, hH[j]);
            hH[j] = fmaf(bcast(a1[j], 4 * k4 + 1), w.y, hH[j]);
            hH[j] = fmaf(bcast(a1[j], 4 * k4 + 2), w.z, hH[j]);
            hH[j] = fmaf(bcast(a1[j], 4 * k4 + 3), w.w, hH[j]);
        }
    }
#pragma unroll 4
    for (int k4 = 0; k4 < 16; ++k4) {
        float4 w = WhiV[(32 + k4) * 64 + c];
#pragma unroll
        for (int j = 0; j < 8; ++j) {
            hH[j] = fmaf(bcast(a2[j], 4 * k4 + 0), w.x, hH[j]);
            hH[j] = fmaf(bcast(a2[j], 4 * k4 + 1), w.y, hH[j]);
            hH[j] = fmaf(bcast(a2[j], 4 * k4 + 2), w.z, hH[j]);
            hH[j] = fmaf(bcast(a2[j], 4 * k4 + 3), w.w, hH[j]);
        }
    }
    {
        float b = bh[c];
#pragma unroll
        for (int j = 0; j < 8; ++j) hH[j] = tanhf(hH[j] + b);
    }

    // ---- P3: az += hH @ Wz.T (cols 0..63) ----
#pragma unroll 4
    for (int k = 0; k < 64; ++k) {
        float4 w = WziV[k * 64 + c];
#pragma unroll
        for (int j = 0; j < 8; ++j) {
            float s = bcast(hH[j], k);
            az0[j] = fmaf(s, w.x, az0[j]);
            az1[j] = fmaf(s, w.y, az1[j]);
            az2[j] = fmaf(s, w.z, az2[j]);
            az3[j] = fmaf(s, w.w, az3[j]);
        }
    }

    // ---- epilogue: gate softmax + mix + write ----
    {
        float b0 = bz[c], b1 = bz[64 + c], b2 = bz[128 + c], b3 = bz[192 + c];
#pragma unroll
        for (int j = 0; j < 8; ++j) {
            int i = row0 + j;
            if (i < M_DIM) {
                float z0 = az0[j] + b0;
                float z1 = az1[j] + b1;
                float z2 = az2[j] + b2;
                float z3 = az3[j] + b3;
                float mx = fmaxf(fmaxf(z0, z1), fmaxf(z2, z3));
                float e0 = expf(z0 - mx), e1 = expf(z1 - mx);
                float e2 = expf(z2 - mx), e3 = expf(z3 - mx);
                float s = e0 + e1 + e2 + e3;
                float h = (e0 * hH[j] + e1 * hl[j] + e2 * hr[j] + e3 * uu[j]) / s;
                embC[(size_t)i * 64 + c] = h;
            }
        }
    }
}

// ---------------------------------------------------------------------------
extern "C" void kernel_launch(void* const* d_in, const int* in_sizes, int n_in,
                              void* d_out, int out_size, void* d_ws, size_t ws_size,
                              hipStream_t stream) {
    const float* contents = (const float*)d_in[0];
    const int*   children = (const int*)d_in[1];
    const float* Wu = (const float*)d_in[2];
    const float* bu = (const float*)d_in[3];
    const float* Wh = (const float*)d_in[4];
    const float* bh = (const float*)d_in[5];
    const float* Wz = (const float*)d_in[6];
    const float* bz = (const float*)d_in[7];
    const float* Wr = (const float*)d_in[8];
    const float* br = (const float*)d_in[9];
    float* out = (float*)d_out;
    float* ws  = (float*)d_ws;

    float* embEven = ws;                               // N*64 floats
    float* Wri = ws + (size_t)N_DIM * H_DIM;           // 192*64*4
    float* Whi = Wri + 192 * 64 * 4;                   // 48*64*4
    float* Wzi = Whi + 48 * 64 * 4;                    // 256*64*4

    const int NPREP = 192 * 64 * 4 + 48 * 64 * 4 + 256 * 64 * 4;
    prep_weights<<<(NPREP + 255) / 256, 256, 0, stream>>>(Wr, Wh, Wz, Wri, Whi, Wzi);

    int ublocks = (N_DIM * H_DIM + 255) / 256;
    int sblocks = (M_DIM + 63) / 64;

    u_kernel<<<ublocks, 256, 0, stream>>>(contents, Wu, bu, embEven);

    for (int l = 1; l < L_DIM; ++l) {
        float* cur        = (l & 1) ? out : embEven;
        const float* prev = (l & 1) ? embEven : out;
        u_kernel<<<ublocks, 256, 0, stream>>>(contents + (size_t)l * N_DIM * F_DIM,
                                              Wu, bu, cur);
        step_kernel<<<sblocks, BT, 0, stream>>>(prev, cur,
                                                children + (size_t)(l - 1) * M_DIM * 2,
                                                (const float4*)Wri, br,
                                                (const float4*)Whi, bh,
                                                (const float4*)Wzi, bz);
    }
}

// Round 4
// 7711.947 us; speedup vs baseline: 1.0225x; 1.0225x over previous
//
#include <hip/hip_runtime.h>

#define L_DIM 16
#define N_DIM 200000
#define M_DIM 100000
#define F_DIM 7
#define H_DIM 64
#define JR 16    // rows per (single-wave) block

// ---------------------------------------------------------------------------
// u = tanh(contents_l @ Wu.T + bu)  for all N rows -> out (N,64)
// ---------------------------------------------------------------------------
__global__ __launch_bounds__(256) void u_kernel(const float* __restrict__ contents_l,
                                                const float* __restrict__ Wu,
                                                const float* __restrict__ bu,
                                                float* __restrict__ out) {
    __shared__ float sWu[H_DIM * F_DIM];
    __shared__ float sbu[H_DIM];
    int t = threadIdx.x;
    for (int idx = t; idx < H_DIM * F_DIM; idx += 256) sWu[idx] = Wu[idx];
    if (t < H_DIM) sbu[t] = bu[t];
    __syncthreads();

    int gid = blockIdx.x * 256 + t;
    int i = gid >> 6;
    int h = gid & 63;
    if (i >= N_DIM) return;
    const float* c = contents_l + (size_t)i * F_DIM;
    float acc = sbu[h];
#pragma unroll
    for (int f = 0; f < F_DIM; ++f) acc = fmaf(c[f], sWu[h * F_DIM + f], acc);
    out[(size_t)i * H_DIM + h] = tanhf(acc);
}

// ---------------------------------------------------------------------------
// Interleaved weight prep (same layouts as R2):
//  Wri[(k*64+c)*4+q] = (q<3) ? Wr[(q*64+c)*192 + k] : 0      (192*64*4)
//  Whi[(k4*64+c)*4+q] = Wh[c*192 + 4*k4+q]                    (48*64*4)
//  Wzi[(k*64+c)*4+q] = Wz[(q*64+c)*256 + k]                   (256*64*4)
// Lane c loads ONE float4 per k containing every weight it needs.
// ---------------------------------------------------------------------------
__global__ void prep_weights(const float* __restrict__ Wr, const float* __restrict__ Wh,
                             const float* __restrict__ Wz,
                             float* __restrict__ Wri, float* __restrict__ Whi,
                             float* __restrict__ Wzi) {
    const int NWri = 192 * 64 * 4, NWhi = 48 * 64 * 4, NWzi = 256 * 64 * 4;
    int idx = blockIdx.x * 256 + threadIdx.x;
    if (idx < NWri) {
        int q = idx & 3, c = (idx >> 2) & 63, k = idx >> 8;
        Wri[idx] = (q < 3) ? Wr[(q * 64 + c) * 192 + k] : 0.f;
    } else if (idx < NWri + NWhi) {
        int m = idx - NWri;
        int q = m & 3, c = (m >> 2) & 63, k4 = m >> 8;
        Whi[m] = Wh[c * 192 + 4 * k4 + q];
    } else if (idx < NWri + NWhi + NWzi) {
        int m = idx - NWri - NWhi;
        int q = m & 3, c = (m >> 2) & 63, k = m >> 8;
        Wzi[m] = Wz[(q * 64 + c) * 256 + k];
    }
}

// ---------------------------------------------------------------------------
// One scan step. Single-wave blocks (64 threads), JR=16 rows per block.
// Lane c owns output column c. Activations staged in LDS; all activation
// reads in the matmul phases are wave-uniform broadcasts (conflict-free).
// All LDS deps are intra-wave; __syncthreads() at phase edges is cheap.
// Weights stream from L2 (one 506KB stream per 16 rows).
// ---------------------------------------------------------------------------
__global__ __launch_bounds__(64) void step_kernel(
    const float* __restrict__ embP,
    float* __restrict__ embC,
    const int* __restrict__ chl,
    const float4* __restrict__ WriV, const float* __restrict__ br,
    const float4* __restrict__ WhiV, const float* __restrict__ bh,
    const float4* __restrict__ WziV, const float* __restrict__ bz)
{
    __shared__ __align__(16) float hhu[JR][196];   // [hL|hR|u], overwritten with r*hhu
    __shared__ __align__(16) float hHs[JR][64];
    const int c = threadIdx.x;                     // 0..63
    const int row0 = blockIdx.x * JR;

    // ---- P0: gather; own column kept in regs ----
    float hl[JR], hr[JR], uu[JR];
#pragma unroll
    for (int j = 0; j < JR; ++j) {
        int i = row0 + j;
        if (i < M_DIM) {
            int iL = chl[2 * i], iR = chl[2 * i + 1];
            hl[j] = embP[(size_t)iL * 64 + c];
            hr[j] = embP[(size_t)iR * 64 + c];
            uu[j] = embC[(size_t)i * 64 + c];
        } else { hl[j] = 0.f; hr[j] = 0.f; uu[j] = 0.f; }
        hhu[j][c]       = hl[j];
        hhu[j][64 + c]  = hr[j];
        hhu[j][128 + c] = uu[j];
    }
    __syncthreads();

    // ---- P1a: a = hhu @ Wr.T (3 r-gate outputs per lane) ----
    float a0[JR], a1[JR], a2[JR];
#pragma unroll
    for (int j = 0; j < JR; ++j) { a0[j] = 0.f; a1[j] = 0.f; a2[j] = 0.f; }
#pragma unroll 2
    for (int k = 0; k < 192; k += 4) {
        float4 w0 = WriV[(k + 0) * 64 + c];
        float4 w1 = WriV[(k + 1) * 64 + c];
        float4 w2 = WriV[(k + 2) * 64 + c];
        float4 w3 = WriV[(k + 3) * 64 + c];
#pragma unroll
        for (int j = 0; j < JR; ++j) {
            float4 a = *(const float4*)&hhu[j][k];   // broadcast read
            a0[j] = fmaf(a.x, w0.x, a0[j]);
            a1[j] = fmaf(a.x, w0.y, a1[j]);
            a2[j] = fmaf(a.x, w0.z, a2[j]);
            a0[j] = fmaf(a.y, w1.x, a0[j]);
            a1[j] = fmaf(a.y, w1.y, a1[j]);
            a2[j] = fmaf(a.y, w1.z, a2[j]);
            a0[j] = fmaf(a.z, w2.x, a0[j]);
            a1[j] = fmaf(a.z, w2.y, a1[j]);
            a2[j] = fmaf(a.z, w2.z, a2[j]);
            a0[j] = fmaf(a.w, w3.x, a0[j]);
            a1[j] = fmaf(a.w, w3.y, a1[j]);
            a2[j] = fmaf(a.w, w3.z, a2[j]);
        }
    }

    // ---- P1b: az = z-partial over hhu columns (Wz k = 64..255) ----
    float az0[JR], az1[JR], az2[JR], az3[JR];
#pragma unroll
    for (int j = 0; j < JR; ++j) { az0[j] = 0.f; az1[j] = 0.f; az2[j] = 0.f; az3[j] = 0.f; }
#pragma unroll 2
    for (int k = 0; k < 192; k += 4) {
        float4 w0 = WziV[(64 + k + 0) * 64 + c];
        float4 w1 = WziV[(64 + k + 1) * 64 + c];
        float4 w2 = WziV[(64 + k + 2) * 64 + c];
        float4 w3 = WziV[(64 + k + 3) * 64 + c];
#pragma unroll
        for (int j = 0; j < JR; ++j) {
            float4 a = *(const float4*)&hhu[j][k];   // broadcast read
            az0[j] = fmaf(a.x, w0.x, az0[j]);
            az1[j] = fmaf(a.x, w0.y, az1[j]);
            az2[j] = fmaf(a.x, w0.z, az2[j]);
            az3[j] = fmaf(a.x, w0.w, az3[j]);
            az0[j] = fmaf(a.y, w1.x, az0[j]);
            az1[j] = fmaf(a.y, w1.y, az1[j]);
            az2[j] = fmaf(a.y, w1.z, az2[j]);
            az3[j] = fmaf(a.y, w1.w, az3[j]);
            az0[j] = fmaf(a.z, w2.x, az0[j]);
            az1[j] = fmaf(a.z, w2.y, az1[j]);
            az2[j] = fmaf(a.z, w2.z, az2[j]);
            az3[j] = fmaf(a.z, w2.w, az3[j]);
            az0[j] = fmaf(a.w, w3.x, az0[j]);
            az1[j] = fmaf(a.w, w3.y, az1[j]);
            az2[j] = fmaf(a.w, w3.z, az2[j]);
            az3[j] = fmaf(a.w, w3.w, az3[j]);
        }
    }
    __syncthreads();   // all lanes done reading hhu

    // ---- r = sigmoid(a + br); overwrite hhu in place with r*hhu ----
    {
        float b0 = br[c], b1 = br[64 + c], b2 = br[128 + c];
#pragma unroll
        for (int j = 0; j < JR; ++j) {
            hhu[j][c]       = hl[j] / (1.f + expf(-(a0[j] + b0)));
            hhu[j][64 + c]  = hr[j] / (1.f + expf(-(a1[j] + b1)));
            hhu[j][128 + c] = uu[j] / (1.f + expf(-(a2[j] + b2)));
        }
    }
    __syncthreads();

    // ---- P2: hH = tanh(rh @ Wh.T + bh) ----
    float hh[JR];
#pragma unroll
    for (int j = 0; j < JR; ++j) hh[j] = 0.f;
#pragma unroll 2
    for (int k4 = 0; k4 < 48; ++k4) {
        float4 w = WhiV[k4 * 64 + c];
#pragma unroll
        for (int j = 0; j < JR; ++j) {
            float4 a = *(const float4*)&hhu[j][k4 * 4];   // broadcast read
            hh[j] = fmaf(a.x, w.x, hh[j]);
            hh[j] = fmaf(a.y, w.y, hh[j]);
            hh[j] = fmaf(a.z, w.z, hh[j]);
            hh[j] = fmaf(a.w, w.w, hh[j]);
        }
    }
    {
        float b = bh[c];
#pragma unroll
        for (int j = 0; j < JR; ++j) {
            hh[j] = tanhf(hh[j] + b);
            hHs[j][c] = hh[j];
        }
    }
    __syncthreads();

    // ---- P3: az += hH @ Wz.T (k = 0..63) ----
#pragma unroll 2
    for (int k = 0; k < 64; k += 4) {
        float4 w0 = WziV[(k + 0) * 64 + c];
        float4 w1 = WziV[(k + 1) * 64 + c];
        float4 w2 = WziV[(k + 2) * 64 + c];
        float4 w3 = WziV[(k + 3) * 64 + c];
#pragma unroll
        for (int j = 0; j < JR; ++j) {
            float4 a = *(const float4*)&hHs[j][k];   // broadcast read
            az0[j] = fmaf(a.x, w0.x, az0[j]);
            az1[j] = fmaf(a.x, w0.y, az1[j]);
            az2[j] = fmaf(a.x, w0.z, az2[j]);
            az3[j] = fmaf(a.x, w0.w, az3[j]);
            az0[j] = fmaf(a.y, w1.x, az0[j]);
            az1[j] = fmaf(a.y, w1.y, az1[j]);
            az2[j] = fmaf(a.y, w1.z, az2[j]);
            az3[j] = fmaf(a.y, w1.w, az3[j]);
            az0[j] = fmaf(a.z, w2.x, az0[j]);
            az1[j] = fmaf(a.z, w2.y, az1[j]);
            az2[j] = fmaf(a.z, w2.z, az2[j]);
            az3[j] = fmaf(a.z, w2.w, az3[j]);
            az0[j] = fmaf(a.w, w3.x, az0[j]);
            az1[j] = fmaf(a.w, w3.y, az1[j]);
            az2[j] = fmaf(a.w, w3.z, az2[j]);
            az3[j] = fmaf(a.w, w3.w, az3[j]);
        }
    }

    // ---- epilogue: gate softmax + mix + write ----
    {
        float b0 = bz[c], b1 = bz[64 + c], b2 = bz[128 + c], b3 = bz[192 + c];
#pragma unroll
        for (int j = 0; j < JR; ++j) {
            int i = row0 + j;
            if (i < M_DIM) {
                float z0 = az0[j] + b0;
                float z1 = az1[j] + b1;
                float z2 = az2[j] + b2;
                float z3 = az3[j] + b3;
                float mx = fmaxf(fmaxf(z0, z1), fmaxf(z2, z3));
                float e0 = expf(z0 - mx), e1 = expf(z1 - mx);
                float e2 = expf(z2 - mx), e3 = expf(z3 - mx);
                float s = e0 + e1 + e2 + e3;
                float h = (e0 * hh[j] + e1 * hl[j] + e2 * hr[j] + e3 * uu[j]) / s;
                embC[(size_t)i * 64 + c] = h;
            }
        }
    }
}

// ---------------------------------------------------------------------------
extern "C" void kernel_launch(void* const* d_in, const int* in_sizes, int n_in,
                              void* d_out, int out_size, void* d_ws, size_t ws_size,
                              hipStream_t stream) {
    const float* contents = (const float*)d_in[0];
    const int*   children = (const int*)d_in[1];
    const float* Wu = (const float*)d_in[2];
    const float* bu = (const float*)d_in[3];
    const float* Wh = (const float*)d_in[4];
    const float* bh = (const float*)d_in[5];
    const float* Wz = (const float*)d_in[6];
    const float* bz = (const float*)d_in[7];
    const float* Wr = (const float*)d_in[8];
    const float* br = (const float*)d_in[9];
    float* out = (float*)d_out;
    float* ws  = (float*)d_ws;

    float* embEven = ws;                               // N*64 floats
    float* Wri = ws + (size_t)N_DIM * H_DIM;           // 192*64*4
    float* Whi = Wri + 192 * 64 * 4;                   // 48*64*4
    float* Wzi = Whi + 48 * 64 * 4;                    // 256*64*4

    const int NPREP = 192 * 64 * 4 + 48 * 64 * 4 + 256 * 64 * 4;
    prep_weights<<<(NPREP + 255) / 256, 256, 0, stream>>>(Wr, Wh, Wz, Wri, Whi, Wzi);

    int ublocks = (N_DIM * H_DIM + 255) / 256;
    int sblocks = (M_DIM + JR - 1) / JR;

    u_kernel<<<ublocks, 256, 0, stream>>>(contents, Wu, bu, embEven);

    for (int l = 1; l < L_DIM; ++l) {
        float* cur        = (l & 1) ? out : embEven;
        const float* prev = (l & 1) ? embEven : out;
        u_kernel<<<ublocks, 256, 0, stream>>>(contents + (size_t)l * N_DIM * F_DIM,
                                              Wu, bu, cur);
        step_kernel<<<sblocks, 64, 0, stream>>>(prev, cur,
                                                children + (size_t)(l - 1) * M_DIM * 2,
                                                (const float4*)Wri, br,
                                                (const float4*)Whi, bh,
                                                (const float4*)Wzi, bz);
    }
}

// Round 5
// 4091.999 us; speedup vs baseline: 1.9271x; 1.8846x over previous
//
#include <hip/hip_runtime.h>

#define L_DIM 16
#define N_DIM 200000
#define M_DIM 100000
#define F_DIM 7
#define H_DIM 64

typedef _Float16 f16;
typedef __attribute__((ext_vector_type(8))) _Float16 f16x8;
typedef __attribute__((ext_vector_type(4))) float f32x4;

#define MFMA(a, b, c) __builtin_amdgcn_mfma_f32_16x16x32_f16((a), (b), (c), 0, 0, 0)

// pack sizes (f16 elements)
#define NR_PK (192 * 192)
#define NH_PK (64 * 192)
#define NZ_PK (256 * 256)

// ---------------------------------------------------------------------------
// u = tanh(contents_l @ Wu.T + bu)  for all N rows -> out (N,64)  [fp32]
// ---------------------------------------------------------------------------
__global__ __launch_bounds__(256) void u_kernel(const float* __restrict__ contents_l,
                                                const float* __restrict__ Wu,
                                                const float* __restrict__ bu,
                                                float* __restrict__ out) {
    __shared__ float sWu[H_DIM * F_DIM];
    __shared__ float sbu[H_DIM];
    int t = threadIdx.x;
    for (int idx = t; idx < H_DIM * F_DIM; idx += 256) sWu[idx] = Wu[idx];
    if (t < H_DIM) sbu[t] = bu[t];
    __syncthreads();

    int gid = blockIdx.x * 256 + t;
    int i = gid >> 6;
    int h = gid & 63;
    if (i >= N_DIM) return;
    const float* c = contents_l + (size_t)i * F_DIM;
    float acc = sbu[h];
#pragma unroll
    for (int f = 0; f < F_DIM; ++f) acc = fmaf(c[f], sWu[h * F_DIM + f], acc);
    float e = __expf(2.f * acc);
    out[(size_t)i * H_DIM + h] = 1.f - 2.f / (e + 1.f);
}

// ---------------------------------------------------------------------------
// Pack weights into MFMA B-fragment order, fp16.
// For W (O x K) used as B[k][n] = W[n][k]:
//   tile index = nt*KS + ks ; element = (tile*64 + lane)*8 + j
//   value = W[(nt*16 + (lane&15)) * K + ks*32 + (lane>>4)*8 + j]
// The same (lane,j)->k rule is used for A fragments, so the contraction is
// correct for any bijective hardware k-mapping.
// ---------------------------------------------------------------------------
__global__ void prep_pack(const float* __restrict__ Wr, const float* __restrict__ Wh,
                          const float* __restrict__ Wz, f16* __restrict__ out) {
    int idx = blockIdx.x * 256 + threadIdx.x;
    if (idx >= NR_PK + NH_PK + NZ_PK) return;
    int e, Kdim, KS;
    const float* W;
    f16* dst;
    if (idx < NR_PK) { e = idx; W = Wr; Kdim = 192; KS = 6; dst = out; }
    else if (idx < NR_PK + NH_PK) { e = idx - NR_PK; W = Wh; Kdim = 192; KS = 6; dst = out + NR_PK; }
    else { e = idx - NR_PK - NH_PK; W = Wz; Kdim = 256; KS = 8; dst = out + NR_PK + NH_PK; }
    int j = e & 7;
    int l = (e >> 3) & 63;
    int tile = e >> 9;
    int ks = tile % KS;
    int nt = tile / KS;
    int k = ks * 32 + (l >> 4) * 8 + j;
    int n = nt * 16 + (l & 15);
    dst[e] = (f16)W[n * Kdim + k];
}

// convert 16 consecutive fp32 -> 16 fp16 in LDS (two b128 writes)
__device__ __forceinline__ void g16(const float* __restrict__ p, f16* __restrict__ d) {
    const float4* p4 = (const float4*)p;
    float4 a = p4[0], b = p4[1], c = p4[2], e = p4[3];
    f16x8 h0 = {(f16)a.x, (f16)a.y, (f16)a.z, (f16)a.w,
                (f16)b.x, (f16)b.y, (f16)b.z, (f16)b.w};
    f16x8 h1 = {(f16)c.x, (f16)c.y, (f16)c.z, (f16)c.w,
                (f16)e.x, (f16)e.y, (f16)e.z, (f16)e.w};
    *(f16x8*)d = h0;
    *(f16x8*)(d + 8) = h1;
}

// ---------------------------------------------------------------------------
// Fused step: 256 threads = 4 waves; 64 rows/block, 16 rows/wave.
// Each wave is fully self-contained (gather->GEMM1->GEMM2->GEMM3->epilogue
// all on its own 16 rows) -> NO barriers, only wave-order LDS dependencies.
// GEMMs use v_mfma_f32_16x16x32_f16; accumulation fp32; recurrence path fp32.
// ---------------------------------------------------------------------------
__global__ __launch_bounds__(256) void step_kernel(
    const float* __restrict__ embP,
    float* __restrict__ embC,
    const int* __restrict__ chl,
    const f16x8* __restrict__ WrPk,
    const f16x8* __restrict__ WhPk,
    const f16x8* __restrict__ WzPk,
    const float* __restrict__ br,
    const float* __restrict__ bh,
    const float* __restrict__ bz)
{
    __shared__ f16 hhu[64][200];   // [hL | hR | u] fp16, padded 192->200
    __shared__ f16 rhs[64][200];   // r * hhu
    __shared__ f16 hHs[64][72];    // h_H fp16, padded 64->72

    const int t = threadIdx.x;
    const int w = t >> 6;          // wave 0..3
    const int l = t & 63;
    const int l15 = l & 15;
    const int g4 = l >> 4;         // 0..3
    const int base = blockIdx.x * 64;

    // ---- gather: 4 lanes per row, 16 cols each ----
    {
        int rloc = w * 16 + (l >> 2);       // 0..63 (wave-local rows)
        int q = l & 3;
        int i = base + rloc;
        if (i < M_DIM) {
            int iL = chl[2 * i], iR = chl[2 * i + 1];
            g16(embP + (size_t)iL * 64 + q * 16, &hhu[rloc][q * 16]);
            g16(embP + (size_t)iR * 64 + q * 16, &hhu[rloc][64 + q * 16]);
            g16(embC + (size_t)i * 64 + q * 16, &hhu[rloc][128 + q * 16]);
        } else {
            f16x8 z = {0, 0, 0, 0, 0, 0, 0, 0};
#pragma unroll
            for (int a = 0; a < 3; ++a) {
                *(f16x8*)&hhu[rloc][a * 64 + q * 16] = z;
                *(f16x8*)&hhu[rloc][a * 64 + q * 16 + 8] = z;
            }
        }
    }

    // ---- A fragments of hhu (reused in GEMM1 and GEMM3) ----
    f16x8 aH[6];
#pragma unroll
    for (int ks = 0; ks < 6; ++ks)
        aH[ks] = *(const f16x8*)&hhu[w * 16 + l15][ks * 32 + g4 * 8];

    // ---- GEMM1: r logits = hhu @ Wr.T ; rhs = sigmoid(.)*hhu ----
#pragma unroll
    for (int nt = 0; nt < 12; ++nt) {
        f32x4 acc = {0.f, 0.f, 0.f, 0.f};
#pragma unroll
        for (int ks = 0; ks < 6; ++ks)
            acc = MFMA(aH[ks], WrPk[(nt * 6 + ks) * 64 + l], acc);
        int col = nt * 16 + l15;
        float bias = br[col];
#pragma unroll
        for (int r = 0; r < 4; ++r) {
            int row = w * 16 + 4 * g4 + r;
            float rv = 1.f / (1.f + __expf(-(acc[r] + bias)));
            float hv = (float)hhu[row][col];
            rhs[row][col] = (f16)(rv * hv);
        }
    }

    // ---- GEMM2: h_H = tanh(rhs @ Wh.T + bh) ----
    {
        f16x8 aR[6];
#pragma unroll
        for (int ks = 0; ks < 6; ++ks)
            aR[ks] = *(const f16x8*)&rhs[w * 16 + l15][ks * 32 + g4 * 8];
#pragma unroll
        for (int nt = 0; nt < 4; ++nt) {
            f32x4 acc = {0.f, 0.f, 0.f, 0.f};
#pragma unroll
            for (int ks = 0; ks < 6; ++ks)
                acc = MFMA(aR[ks], WhPk[(nt * 6 + ks) * 64 + l], acc);
            int col = nt * 16 + l15;
            float bias = bh[col];
#pragma unroll
            for (int r = 0; r < 4; ++r) {
                int row = w * 16 + 4 * g4 + r;
                float x = acc[r] + bias;
                float e = __expf(2.f * x);
                hHs[row][col] = (f16)(1.f - 2.f / (e + 1.f));
            }
        }
    }

    // ---- GEMM3: z = [h_H | hhu] @ Wz.T  (16 n-tiles, K=256) ----
    f32x4 accz[16];
    {
        f16x8 aZ0 = *(const f16x8*)&hHs[w * 16 + l15][g4 * 8];
        f16x8 aZ1 = *(const f16x8*)&hHs[w * 16 + l15][32 + g4 * 8];
#pragma unroll
        for (int nt = 0; nt < 16; ++nt) {
            f32x4 acc = {0.f, 0.f, 0.f, 0.f};
            acc = MFMA(aZ0, WzPk[(nt * 8 + 0) * 64 + l], acc);
            acc = MFMA(aZ1, WzPk[(nt * 8 + 1) * 64 + l], acc);
#pragma unroll
            for (int ks = 2; ks < 8; ++ks)
                acc = MFMA(aH[ks - 2], WzPk[(nt * 8 + ks) * 64 + l], acc);
            accz[nt] = acc;
        }
    }

    // ---- epilogue: softmax over 4 gate groups; mix in fp32; store ----
#pragma unroll
    for (int r = 0; r < 4; ++r) {
        int rowb = w * 16 + 4 * g4 + r;
        int i = base + rowb;
        if (i < M_DIM) {
            int iL = chl[2 * i], iR = chl[2 * i + 1];
#pragma unroll
            for (int T = 0; T < 4; ++T) {
                int col = T * 16 + l15;
                float z0 = accz[T][r]      + bz[col];
                float z1 = accz[T + 4][r]  + bz[64 + col];
                float z2 = accz[T + 8][r]  + bz[128 + col];
                float z3 = accz[T + 12][r] + bz[192 + col];
                float mx = fmaxf(fmaxf(z0, z1), fmaxf(z2, z3));
                float e0 = __expf(z0 - mx), e1 = __expf(z1 - mx);
                float e2 = __expf(z2 - mx), e3 = __expf(z3 - mx);
                float s = e0 + e1 + e2 + e3;
                float hHv = (float)hHs[rowb][col];
                float hLv = embP[(size_t)iL * 64 + col];
                float hRv = embP[(size_t)iR * 64 + col];
                float uv  = embC[(size_t)i * 64 + col];
                float h = (e0 * hHv + e1 * hLv + e2 * hRv + e3 * uv) / s;
                embC[(size_t)i * 64 + col] = h;
            }
        }
    }
}

// ---------------------------------------------------------------------------
extern "C" void kernel_launch(void* const* d_in, const int* in_sizes, int n_in,
                              void* d_out, int out_size, void* d_ws, size_t ws_size,
                              hipStream_t stream) {
    const float* contents = (const float*)d_in[0];
    const int*   children = (const int*)d_in[1];
    const float* Wu = (const float*)d_in[2];
    const float* bu = (const float*)d_in[3];
    const float* Wh = (const float*)d_in[4];
    const float* bh = (const float*)d_in[5];
    const float* Wz = (const float*)d_in[6];
    const float* bz = (const float*)d_in[7];
    const float* Wr = (const float*)d_in[8];
    const float* br = (const float*)d_in[9];
    float* out = (float*)d_out;
    float* ws  = (float*)d_ws;

    float* embEven = ws;                             // N*64 fp32
    f16*   pack    = (f16*)(ws + (size_t)N_DIM * H_DIM);
    const f16x8* WrPk = (const f16x8*)pack;
    const f16x8* WhPk = (const f16x8*)(pack + NR_PK);
    const f16x8* WzPk = (const f16x8*)(pack + NR_PK + NH_PK);

    const int NPK = NR_PK + NH_PK + NZ_PK;
    prep_pack<<<(NPK + 255) / 256, 256, 0, stream>>>(Wr, Wh, Wz, pack);

    int ublocks = (N_DIM * H_DIM + 255) / 256;
    int sblocks = (M_DIM + 63) / 64;

    u_kernel<<<ublocks, 256, 0, stream>>>(contents, Wu, bu, embEven);

    for (int l = 1; l < L_DIM; ++l) {
        float* cur        = (l & 1) ? out : embEven;
        const float* prev = (l & 1) ? embEven : out;
        u_kernel<<<ublocks, 256, 0, stream>>>(contents + (size_t)l * N_DIM * F_DIM,
                                              Wu, bu, cur);
        step_kernel<<<sblocks, 256, 0, stream>>>(prev, cur,
                                                 children + (size_t)(l - 1) * M_DIM * 2,
                                                 WrPk, WhPk, WzPk, br, bh, bz);
    }
}

// Round 6
// 2729.992 us; speedup vs baseline: 2.8885x; 1.4989x over previous
//
#include <hip/hip_runtime.h>

#define L_DIM 16
#define N_DIM 200000
#define M_DIM 100000
#define F_DIM 7
#define H_DIM 64

typedef _Float16 f16;
typedef __attribute__((ext_vector_type(8))) _Float16 f16x8;
typedef __attribute__((ext_vector_type(4))) float f32x4;

#define MFMA(a, b, c) __builtin_amdgcn_mfma_f32_16x16x32_f16((a), (b), (c), 0, 0, 0)

// pack sizes (f16 elements)
#define NR_PK (192 * 192)
#define NH_PK (64 * 192)
#define NZ_PK (256 * 256)

// ---------------------------------------------------------------------------
// u = tanh(contents_l @ Wu.T + bu)  for all N rows -> out (N,64)  [fp32]
// ---------------------------------------------------------------------------
__global__ __launch_bounds__(256) void u_kernel(const float* __restrict__ contents_l,
                                                const float* __restrict__ Wu,
                                                const float* __restrict__ bu,
                                                float* __restrict__ out) {
    __shared__ float sWu[H_DIM * F_DIM];
    __shared__ float sbu[H_DIM];
    int t = threadIdx.x;
    for (int idx = t; idx < H_DIM * F_DIM; idx += 256) sWu[idx] = Wu[idx];
    if (t < H_DIM) sbu[t] = bu[t];
    __syncthreads();

    int gid = blockIdx.x * 256 + t;
    int i = gid >> 6;
    int h = gid & 63;
    if (i >= N_DIM) return;
    const float* c = contents_l + (size_t)i * F_DIM;
    float acc = sbu[h];
#pragma unroll
    for (int f = 0; f < F_DIM; ++f) acc = fmaf(c[f], sWu[h * F_DIM + f], acc);
    float e = __expf(2.f * acc);
    out[(size_t)i * H_DIM + h] = 1.f - 2.f / (e + 1.f);
}

// ---------------------------------------------------------------------------
// Pack weights into MFMA B-fragment order, fp16 (same scheme as R5).
//   tile = nt*KS + ks ; element = (tile*64 + lane)*8 + j
//   value = W[(nt*16 + (lane&15)) * K + ks*32 + (lane>>4)*8 + j]
// ---------------------------------------------------------------------------
__global__ void prep_pack(const float* __restrict__ Wr, const float* __restrict__ Wh,
                          const float* __restrict__ Wz, f16* __restrict__ out) {
    int idx = blockIdx.x * 256 + threadIdx.x;
    if (idx >= NR_PK + NH_PK + NZ_PK) return;
    int e, Kdim, KS;
    const float* W;
    f16* dst;
    if (idx < NR_PK) { e = idx; W = Wr; Kdim = 192; KS = 6; dst = out; }
    else if (idx < NR_PK + NH_PK) { e = idx - NR_PK; W = Wh; Kdim = 192; KS = 6; dst = out + NR_PK; }
    else { e = idx - NR_PK - NH_PK; W = Wz; Kdim = 256; KS = 8; dst = out + NR_PK + NH_PK; }
    int j = e & 7;
    int l = (e >> 3) & 63;
    int tile = e >> 9;
    int ks = tile % KS;
    int nt = tile / KS;
    int k = ks * 32 + (l >> 4) * 8 + j;
    int n = nt * 16 + (l & 15);
    dst[e] = (f16)W[n * Kdim + k];
}

// convert 16 consecutive fp32 -> 16 fp16 in LDS (two b128 writes)
__device__ __forceinline__ void g16(const float* __restrict__ p, f16* __restrict__ d) {
    const float4* p4 = (const float4*)p;
    float4 a = p4[0], b = p4[1], c = p4[2], e = p4[3];
    f16x8 h0 = {(f16)a.x, (f16)a.y, (f16)a.z, (f16)a.w,
                (f16)b.x, (f16)b.y, (f16)b.z, (f16)b.w};
    f16x8 h1 = {(f16)c.x, (f16)c.y, (f16)c.z, (f16)c.w,
                (f16)e.x, (f16)e.y, (f16)e.z, (f16)e.w};
    *(f16x8*)d = h0;
    *(f16x8*)(d + 8) = h1;
}

// ---------------------------------------------------------------------------
// Fused step: ONE wave per block, 16 rows. LDS ~9 KB -> occupancy is
// VGPR-bound (target <=128 -> 4 waves/SIMD). No barriers, no bounds checks
// (M = 6250*16 exactly). GEMM3 fused with epilogue per 16-col group to keep
// only 4 gate accumulators live.
// ---------------------------------------------------------------------------
__global__ __launch_bounds__(64) void step_kernel(
    const float* __restrict__ embP,
    float* __restrict__ embC,
    const int* __restrict__ chl,
    const f16x8* __restrict__ WrPk,
    const f16x8* __restrict__ WhPk,
    const f16x8* __restrict__ WzPk,
    const float* __restrict__ br,
    const float* __restrict__ bh,
    const float* __restrict__ bz)
{
    __shared__ f16 hhu[16][200];   // [hL | hR | u]; overwritten with r*hhu in place
    __shared__ f16 hHs[16][72];
    __shared__ int iLs[16], iRs[16];

    const int l = threadIdx.x;
    const int l15 = l & 15;
    const int g4 = l >> 4;         // 0..3
    const int base = blockIdx.x * 16;

    // ---- gather: 4 lanes per row, 16 f32->f16 each ----
    {
        int rloc = l >> 2;          // 0..15
        int q = l & 3;
        int i = base + rloc;
        int iL = chl[2 * i], iR = chl[2 * i + 1];
        if (q == 0) { iLs[rloc] = iL; iRs[rloc] = iR; }
        g16(embP + (size_t)iL * 64 + q * 16, &hhu[rloc][q * 16]);
        g16(embP + (size_t)iR * 64 + q * 16, &hhu[rloc][64 + q * 16]);
        g16(embC + (size_t)i  * 64 + q * 16, &hhu[rloc][128 + q * 16]);
    }

    // ---- A fragments of original hhu (used by GEMM1 and GEMM3) ----
    f16x8 aH[6];
#pragma unroll
    for (int ks = 0; ks < 6; ++ks)
        aH[ks] = *(const f16x8*)&hhu[l15][ks * 32 + g4 * 8];

    // ---- GEMM1: r = sigmoid(hhu @ Wr.T + br); hhu <- r*hhu (in place) ----
#pragma unroll
    for (int nt = 0; nt < 12; ++nt) {
        f32x4 acc = {0.f, 0.f, 0.f, 0.f};
#pragma unroll
        for (int ks = 0; ks < 6; ++ks)
            acc = MFMA(aH[ks], WrPk[(nt * 6 + ks) * 64 + l], acc);
        int col = nt * 16 + l15;
        float bias = br[col];
#pragma unroll
        for (int r = 0; r < 4; ++r) {
            int row = 4 * g4 + r;
            float rv = 1.f / (1.f + __expf(-(acc[r] + bias)));
            float hv = (float)hhu[row][col];          // original, read-before-write
            hhu[row][col] = (f16)(rv * hv);
        }
    }

    // ---- GEMM2: h_H = tanh((r*hhu) @ Wh.T + bh) ----
    {
        f16x8 aR[6];
#pragma unroll
        for (int ks = 0; ks < 6; ++ks)
            aR[ks] = *(const f16x8*)&hhu[l15][ks * 32 + g4 * 8];
#pragma unroll
        for (int nt = 0; nt < 4; ++nt) {
            f32x4 acc = {0.f, 0.f, 0.f, 0.f};
#pragma unroll
            for (int ks = 0; ks < 6; ++ks)
                acc = MFMA(aR[ks], WhPk[(nt * 6 + ks) * 64 + l], acc);
            int col = nt * 16 + l15;
            float bias = bh[col];
#pragma unroll
            for (int r = 0; r < 4; ++r) {
                int row = 4 * g4 + r;
                float x = acc[r] + bias;
                float e = __expf(2.f * x);
                hHs[row][col] = (f16)(1.f - 2.f / (e + 1.f));
            }
        }
    }

    // ---- GEMM3 + fused epilogue, per 16-col group T ----
    f16x8 aZ0 = *(const f16x8*)&hHs[l15][g4 * 8];
    f16x8 aZ1 = *(const f16x8*)&hHs[l15][32 + g4 * 8];
#pragma unroll
    for (int T = 0; T < 4; ++T) {
        f32x4 ac[4];
#pragma unroll
        for (int g = 0; g < 4; ++g) {
            int nt = g * 4 + T;                 // col tile (g*64 + T*16)/16
            f32x4 acc = {0.f, 0.f, 0.f, 0.f};
            acc = MFMA(aZ0, WzPk[(nt * 8 + 0) * 64 + l], acc);
            acc = MFMA(aZ1, WzPk[(nt * 8 + 1) * 64 + l], acc);
#pragma unroll
            for (int ks = 2; ks < 8; ++ks)
                acc = MFMA(aH[ks - 2], WzPk[(nt * 8 + ks) * 64 + l], acc);
            ac[g] = acc;
        }
        int col = T * 16 + l15;
        float b0 = bz[col], b1 = bz[64 + col], b2 = bz[128 + col], b3 = bz[192 + col];
#pragma unroll
        for (int r = 0; r < 4; ++r) {
            int row = 4 * g4 + r;
            int i = base + row;
            int iL = iLs[row], iR = iRs[row];
            float z0 = ac[0][r] + b0;
            float z1 = ac[1][r] + b1;
            float z2 = ac[2][r] + b2;
            float z3 = ac[3][r] + b3;
            float mx = fmaxf(fmaxf(z0, z1), fmaxf(z2, z3));
            float e0 = __expf(z0 - mx), e1 = __expf(z1 - mx);
            float e2 = __expf(z2 - mx), e3 = __expf(z3 - mx);
            float s = e0 + e1 + e2 + e3;
            float hHv = (float)hHs[row][col];
            float hLv = embP[(size_t)iL * 64 + col];
            float hRv = embP[(size_t)iR * 64 + col];
            float uv  = embC[(size_t)i  * 64 + col];   // original u, read-before-write
            embC[(size_t)i * 64 + col] = (e0 * hHv + e1 * hLv + e2 * hRv + e3 * uv) / s;
        }
    }
}

// ---------------------------------------------------------------------------
extern "C" void kernel_launch(void* const* d_in, const int* in_sizes, int n_in,
                              void* d_out, int out_size, void* d_ws, size_t ws_size,
                              hipStream_t stream) {
    const float* contents = (const float*)d_in[0];
    const int*   children = (const int*)d_in[1];
    const float* Wu = (const float*)d_in[2];
    const float* bu = (const float*)d_in[3];
    const float* Wh = (const float*)d_in[4];
    const float* bh = (const float*)d_in[5];
    const float* Wz = (const float*)d_in[6];
    const float* bz = (const float*)d_in[7];
    const float* Wr = (const float*)d_in[8];
    const float* br = (const float*)d_in[9];
    float* out = (float*)d_out;
    float* ws  = (float*)d_ws;

    float* embEven = ws;                             // N*64 fp32
    f16*   pack    = (f16*)(ws + (size_t)N_DIM * H_DIM);
    const f16x8* WrPk = (const f16x8*)pack;
    const f16x8* WhPk = (const f16x8*)(pack + NR_PK);
    const f16x8* WzPk = (const f16x8*)(pack + NR_PK + NH_PK);

    const int NPK = NR_PK + NH_PK + NZ_PK;
    prep_pack<<<(NPK + 255) / 256, 256, 0, stream>>>(Wr, Wh, Wz, pack);

    int ublocks = (N_DIM * H_DIM + 255) / 256;
    int sblocks = M_DIM / 16;    // 6250 exactly

    u_kernel<<<ublocks, 256, 0, stream>>>(contents, Wu, bu, embEven);

    for (int l = 1; l < L_DIM; ++l) {
        float* cur        = (l & 1) ? out : embEven;
        const float* prev = (l & 1) ? embEven : out;
        u_kernel<<<ublocks, 256, 0, stream>>>(contents + (size_t)l * N_DIM * F_DIM,
                                              Wu, bu, cur);
        step_kernel<<<sblocks, 64, 0, stream>>>(prev, cur,
                                                children + (size_t)(l - 1) * M_DIM * 2,
                                                WrPk, WhPk, WzPk, br, bh, bz);
    }
}

// Round 7
// 2130.057 us; speedup vs baseline: 3.7021x; 1.2817x over previous
//
#include <hip/hip_runtime.h>

#define L_DIM 16
#define N_DIM 200000
#define M_DIM 100000
#define F_DIM 7
#define H_DIM 64

typedef _Float16 f16;
typedef __attribute__((ext_vector_type(8))) _Float16 f16x8;
typedef __attribute__((ext_vector_type(4))) float f32x4;

#define MFMA(a, b, c) __builtin_amdgcn_mfma_f32_16x16x32_f16((a), (b), (c), 0, 0, 0)

// pack sizes (f16 elements)
#define NR_PK (192 * 192)
#define NH_PK (64 * 192)
#define NZ_PK (256 * 256)

#define RPAD 200   // f16 row stride for r exchange (16B-aligned rows)
#define HPAD 72    // f16 row stride for hH exchange

// ---------------------------------------------------------------------------
// u = tanh(contents_l @ Wu.T + bu)  for all N rows -> out (N,64)  [fp32]
// ---------------------------------------------------------------------------
__global__ __launch_bounds__(256) void u_kernel(const float* __restrict__ contents_l,
                                                const float* __restrict__ Wu,
                                                const float* __restrict__ bu,
                                                float* __restrict__ out) {
    __shared__ float sWu[H_DIM * F_DIM];
    __shared__ float sbu[H_DIM];
    int t = threadIdx.x;
    for (int idx = t; idx < H_DIM * F_DIM; idx += 256) sWu[idx] = Wu[idx];
    if (t < H_DIM) sbu[t] = bu[t];
    __syncthreads();

    int gid = blockIdx.x * 256 + t;
    int i = gid >> 6;
    int h = gid & 63;
    if (i >= N_DIM) return;
    const float* c = contents_l + (size_t)i * F_DIM;
    float acc = sbu[h];
#pragma unroll
    for (int f = 0; f < F_DIM; ++f) acc = fmaf(c[f], sWu[h * F_DIM + f], acc);
    float e = __expf(2.f * acc);
    out[(size_t)i * H_DIM + h] = 1.f - 2.f / (e + 1.f);
}

// ---------------------------------------------------------------------------
// Pack weights into MFMA B-fragment order, fp16 (same scheme as R5/R6):
//   tile = nt*KS + ks ; element = (tile*64 + lane)*8 + j
//   value = W[(nt*16 + (lane&15)) * K + ks*32 + (lane>>4)*8 + j]
// ---------------------------------------------------------------------------
__global__ void prep_pack(const float* __restrict__ Wr, const float* __restrict__ Wh,
                          const float* __restrict__ Wz, f16* __restrict__ out) {
    int idx = blockIdx.x * 256 + threadIdx.x;
    if (idx >= NR_PK + NH_PK + NZ_PK) return;
    int e, Kdim, KS;
    const float* W;
    f16* dst;
    if (idx < NR_PK) { e = idx; W = Wr; Kdim = 192; KS = 6; dst = out; }
    else if (idx < NR_PK + NH_PK) { e = idx - NR_PK; W = Wh; Kdim = 192; KS = 6; dst = out + NR_PK; }
    else { e = idx - NR_PK - NH_PK; W = Wz; Kdim = 256; KS = 8; dst = out + NR_PK + NH_PK; }
    int j = e & 7;
    int l = (e >> 3) & 63;
    int tile = e >> 9;
    int ks = tile % KS;
    int nt = tile / KS;
    int k = ks * 32 + (l >> 4) * 8 + j;
    int n = nt * 16 + (l & 15);
    dst[e] = (f16)W[n * Kdim + k];
}

// load 8 consecutive f32 and convert to one f16x8 fragment
__device__ __forceinline__ f16x8 cvt8(const float* __restrict__ p) {
    float4 a = *(const float4*)p;
    float4 b = *(const float4*)(p + 4);
    f16x8 h = {(f16)a.x, (f16)a.y, (f16)a.z, (f16)a.w,
               (f16)b.x, (f16)b.y, (f16)b.z, (f16)b.w};
    return h;
}

// ---------------------------------------------------------------------------
// Fused step: 256 thr = 4 waves; each wave independently handles 32 rows
// (two 16-row groups rg=0,1 SHARING every B tile -> 2x arithmetic intensity).
// Gather loads A-fragments straight into registers (no LDS round-trip).
// LDS: per-wave union buffer for the two C->A layout exchanges (r, then hH).
// No barriers anywhere (all LDS deps are wave-local).
// ---------------------------------------------------------------------------
__global__ __launch_bounds__(256) void step_kernel(
    const float* __restrict__ embP,
    float* __restrict__ embC,
    const int* __restrict__ chl,
    const f16x8* __restrict__ WrPk,
    const f16x8* __restrict__ WhPk,
    const f16x8* __restrict__ WzPk,
    const float* __restrict__ br,
    const float* __restrict__ bh,
    const float* __restrict__ bz)
{
    __shared__ f16 xbuf[4][32 * RPAD];   // per-wave union: r[32][RPAD] then hH[32][HPAD]
    __shared__ int idxs[4][32][2];

    const int t = threadIdx.x;
    const int w = t >> 6;
    const int l = t & 63;
    const int l15 = l & 15;
    const int g4 = l >> 4;                    // 0..3
    const int wbase = blockIdx.x * 128 + w * 32;

    f16* rbuf = &xbuf[w][0];

    // ---- gather: A-fragments of [hL|hR|u] straight to registers ----
    f16x8 aH[2][6];
#pragma unroll
    for (int rg = 0; rg < 2; ++rg) {
        int row = rg * 16 + l15;
        int i = wbase + row;
        int ic = i < M_DIM ? i : M_DIM - 1;
        int iL = chl[2 * ic], iR = chl[2 * ic + 1];
        if (g4 == 0) { idxs[w][row][0] = iL; idxs[w][row][1] = iR; }
        const float* pL = embP + (size_t)iL * 64;
        const float* pR = embP + (size_t)iR * 64;
        const float* pU = embC + (size_t)ic * 64;
        aH[rg][0] = cvt8(pL + g4 * 8);
        aH[rg][1] = cvt8(pL + 32 + g4 * 8);
        aH[rg][2] = cvt8(pR + g4 * 8);
        aH[rg][3] = cvt8(pR + 32 + g4 * 8);
        aH[rg][4] = cvt8(pU + g4 * 8);
        aH[rg][5] = cvt8(pU + 32 + g4 * 8);
    }

    // ---- GEMM1: r = sigmoid(hhu @ Wr.T + br) -> rbuf (C-layout, f16) ----
#pragma unroll
    for (int nt = 0; nt < 12; ++nt) {
        f16x8 bb[6];
#pragma unroll
        for (int ks = 0; ks < 6; ++ks) bb[ks] = WrPk[(nt * 6 + ks) * 64 + l];
        f32x4 ac0 = {0.f, 0.f, 0.f, 0.f}, ac1 = {0.f, 0.f, 0.f, 0.f};
#pragma unroll
        for (int ks = 0; ks < 6; ++ks) {
            ac0 = MFMA(aH[0][ks], bb[ks], ac0);
            ac1 = MFMA(aH[1][ks], bb[ks], ac1);
        }
        int col = nt * 16 + l15;
        float bias = br[col];
#pragma unroll
        for (int r = 0; r < 4; ++r) {
            float r0 = 1.f / (1.f + __expf(-(ac0[r] + bias)));
            float r1 = 1.f / (1.f + __expf(-(ac1[r] + bias)));
            rbuf[(4 * g4 + r) * RPAD + col] = (f16)r0;
            rbuf[(16 + 4 * g4 + r) * RPAD + col] = (f16)r1;
        }
    }

    // ---- rebuild rh in A-space: aR = aH (regs) * r (LDS, A-positions) ----
    f16x8 aR[2][6];
#pragma unroll
    for (int rg = 0; rg < 2; ++rg)
#pragma unroll
        for (int ks = 0; ks < 6; ++ks) {
            f16x8 rv = *(const f16x8*)&rbuf[(rg * 16 + l15) * RPAD + ks * 32 + g4 * 8];
            aR[rg][ks] = aH[rg][ks] * rv;
        }

    // ---- GEMM2: hH = tanh(rh @ Wh.T + bh); keep C-vals in regs + LDS f16 ----
    f32x4 hc[2][4];
#pragma unroll
    for (int nt = 0; nt < 4; ++nt) {
        f16x8 bb[6];
#pragma unroll
        for (int ks = 0; ks < 6; ++ks) bb[ks] = WhPk[(nt * 6 + ks) * 64 + l];
        f32x4 ac0 = {0.f, 0.f, 0.f, 0.f}, ac1 = {0.f, 0.f, 0.f, 0.f};
#pragma unroll
        for (int ks = 0; ks < 6; ++ks) {
            ac0 = MFMA(aR[0][ks], bb[ks], ac0);
            ac1 = MFMA(aR[1][ks], bb[ks], ac1);
        }
        int col = nt * 16 + l15;
        float bias = bh[col];
#pragma unroll
        for (int r = 0; r < 4; ++r) {
            float e0 = __expf(2.f * (ac0[r] + bias));
            float e1 = __expf(2.f * (ac1[r] + bias));
            float t0 = 1.f - 2.f / (e0 + 1.f);
            float t1 = 1.f - 2.f / (e1 + 1.f);
            hc[0][nt][r] = t0;
            hc[1][nt][r] = t1;
            rbuf[(4 * g4 + r) * HPAD + col] = (f16)t0;          // union reuse
            rbuf[(16 + 4 * g4 + r) * HPAD + col] = (f16)t1;
        }
    }

    // ---- hH A-fragments ----
    f16x8 aZ[2][2];
#pragma unroll
    for (int rg = 0; rg < 2; ++rg) {
        aZ[rg][0] = *(const f16x8*)&rbuf[(rg * 16 + l15) * HPAD + g4 * 8];
        aZ[rg][1] = *(const f16x8*)&rbuf[(rg * 16 + l15) * HPAD + 32 + g4 * 8];
    }

    // ---- GEMM3 + fused epilogue per 16-col group T ----
#pragma unroll
    for (int T = 0; T < 4; ++T) {
        f32x4 ac[2][4];
#pragma unroll
        for (int g = 0; g < 4; ++g) {
            int nt = g * 4 + T;
            f16x8 bb[8];
#pragma unroll
            for (int ks = 0; ks < 8; ++ks) bb[ks] = WzPk[(nt * 8 + ks) * 64 + l];
            f32x4 a0 = {0.f, 0.f, 0.f, 0.f}, a1 = {0.f, 0.f, 0.f, 0.f};
            a0 = MFMA(aZ[0][0], bb[0], a0);
            a1 = MFMA(aZ[1][0], bb[0], a1);
            a0 = MFMA(aZ[0][1], bb[1], a0);
            a1 = MFMA(aZ[1][1], bb[1], a1);
#pragma unroll
            for (int ks = 2; ks < 8; ++ks) {
                a0 = MFMA(aH[0][ks - 2], bb[ks], a0);
                a1 = MFMA(aH[1][ks - 2], bb[ks], a1);
            }
            ac[0][g] = a0;
            ac[1][g] = a1;
        }
        int col = T * 16 + l15;
        float b0 = bz[col], b1 = bz[64 + col], b2 = bz[128 + col], b3 = bz[192 + col];
#pragma unroll
        for (int rg = 0; rg < 2; ++rg)
#pragma unroll
            for (int r = 0; r < 4; ++r) {
                int row = rg * 16 + 4 * g4 + r;
                int i = wbase + row;
                if (i < M_DIM) {
                    int iL = idxs[w][row][0], iR = idxs[w][row][1];
                    float z0 = ac[rg][0][r] + b0;
                    float z1 = ac[rg][1][r] + b1;
                    float z2 = ac[rg][2][r] + b2;
                    float z3 = ac[rg][3][r] + b3;
                    float mx = fmaxf(fmaxf(z0, z1), fmaxf(z2, z3));
                    float e0 = __expf(z0 - mx), e1 = __expf(z1 - mx);
                    float e2 = __expf(z2 - mx), e3 = __expf(z3 - mx);
                    float s = e0 + e1 + e2 + e3;
                    float hHv = hc[rg][T][r];
                    float hLv = embP[(size_t)iL * 64 + col];
                    float hRv = embP[(size_t)iR * 64 + col];
                    float uv  = embC[(size_t)i  * 64 + col];   // read-before-write
                    embC[(size_t)i * 64 + col] = (e0 * hHv + e1 * hLv + e2 * hRv + e3 * uv) / s;
                }
            }
    }
}

// ---------------------------------------------------------------------------
extern "C" void kernel_launch(void* const* d_in, const int* in_sizes, int n_in,
                              void* d_out, int out_size, void* d_ws, size_t ws_size,
                              hipStream_t stream) {
    const float* contents = (const float*)d_in[0];
    const int*   children = (const int*)d_in[1];
    const float* Wu = (const float*)d_in[2];
    const float* bu = (const float*)d_in[3];
    const float* Wh = (const float*)d_in[4];
    const float* bh = (const float*)d_in[5];
    const float* Wz = (const float*)d_in[6];
    const float* bz = (const float*)d_in[7];
    const float* Wr = (const float*)d_in[8];
    const float* br = (const float*)d_in[9];
    float* out = (float*)d_out;
    float* ws  = (float*)d_ws;

    float* embEven = ws;                             // N*64 fp32
    f16*   pack    = (f16*)(ws + (size_t)N_DIM * H_DIM);
    const f16x8* WrPk = (const f16x8*)pack;
    const f16x8* WhPk = (const f16x8*)(pack + NR_PK);
    const f16x8* WzPk = (const f16x8*)(pack + NR_PK + NH_PK);

    const int NPK = NR_PK + NH_PK + NZ_PK;
    prep_pack<<<(NPK + 255) / 256, 256, 0, stream>>>(Wr, Wh, Wz, pack);

    int ublocks = (N_DIM * H_DIM + 255) / 256;
    int sblocks = (M_DIM + 127) / 128;   // 782 blocks of 4 waves x 32 rows

    u_kernel<<<ublocks, 256, 0, stream>>>(contents, Wu, bu, embEven);

    for (int l = 1; l < L_DIM; ++l) {
        float* cur        = (l & 1) ? out : embEven;
        const float* prev = (l & 1) ? embEven : out;
        u_kernel<<<ublocks, 256, 0, stream>>>(contents + (size_t)l * N_DIM * F_DIM,
                                              Wu, bu, cur);
        step_kernel<<<sblocks, 256, 0, stream>>>(prev, cur,
                                                 children + (size_t)(l - 1) * M_DIM * 2,
                                                 WrPk, WhPk, WzPk, br, bh, bz);
    }
}

// Round 8
// 1853.531 us; speedup vs baseline: 4.2544x; 1.1492x over previous
//
#include <hip/hip_runtime.h>

#define L_DIM 16
#define N_DIM 200000
#define M_DIM 100000
#define F_DIM 7
#define H_DIM 64

typedef _Float16 f16;
typedef __attribute__((ext_vector_type(8))) _Float16 f16x8;
typedef __attribute__((ext_vector_type(4))) float f32x4;

#define MFMA(a,b,c) __builtin_amdgcn_mfma_f32_16x16x32_f16((a),(b),(c),0,0,0)

// pack sizes (f16 elements)
#define NR_PK (192 * 192)
#define NH_PK (64 * 192)
#define NZ_PK (256 * 256)

__device__ __forceinline__ float tanh_(float x) {
    float e = __expf(2.f * x);
    return 1.f - 2.f / (e + 1.f);
}

// ---------------------------------------------------------------------------
// u = tanh(contents_l @ Wu.T + bu)  for all N rows -> out (N,64)  [fp32]
// ---------------------------------------------------------------------------
__global__ __launch_bounds__(256) void u_kernel(const float* __restrict__ contents_l,
                                                const float* __restrict__ Wu,
                                                const float* __restrict__ bu,
                                                float* __restrict__ out) {
    __shared__ float sWu[H_DIM * F_DIM];
    __shared__ float sbu[H_DIM];
    int t = threadIdx.x;
    for (int idx = t; idx < H_DIM * F_DIM; idx += 256) sWu[idx] = Wu[idx];
    if (t < H_DIM) sbu[t] = bu[t];
    __syncthreads();

    int gid = blockIdx.x * 256 + t;
    int i = gid >> 6;
    int h = gid & 63;
    if (i >= N_DIM) return;
    const float* c = contents_l + (size_t)i * F_DIM;
    float acc = sbu[h];
#pragma unroll
    for (int f = 0; f < F_DIM; ++f) acc = fmaf(c[f], sWu[h * F_DIM + f], acc);
    out[(size_t)i * H_DIM + h] = tanh_(acc);
}

// ---------------------------------------------------------------------------
// Pack weights into MFMA fragment order with the custom2 k-rule:
//   koff(g4,j) = (j<4) ? 4*g4 + j : 16 + 4*g4 + (j-4)        (bijective over 32)
//   tile = t16*KS + ks ; element = (tile*64 + lane)*8 + j
//   value = W[16*t16 + (lane&15)][32*ks + koff(lane>>4, j)]
// Used for BOTH A- and B-roles (fragment layouts are symmetric).
// ---------------------------------------------------------------------------
__global__ void prep_pack(const float* __restrict__ Wr, const float* __restrict__ Wh,
                          const float* __restrict__ Wz, f16* __restrict__ out) {
    int idx = blockIdx.x * 256 + threadIdx.x;
    if (idx >= NR_PK + NH_PK + NZ_PK) return;
    int e, Kdim, KS;
    const float* W;
    f16* dst;
    if (idx < NR_PK) { e = idx; W = Wr; Kdim = 192; KS = 6; dst = out; }
    else if (idx < NR_PK + NH_PK) { e = idx - NR_PK; W = Wh; Kdim = 192; KS = 6; dst = out + NR_PK; }
    else { e = idx - NR_PK - NH_PK; W = Wz; Kdim = 256; KS = 8; dst = out + NR_PK + NH_PK; }
    int j = e & 7;
    int l = (e >> 3) & 63;
    int tile = e >> 9;
    int ks = tile % KS;
    int t16 = tile / KS;
    int g4 = l >> 4;
    int koff = (j < 4) ? (4 * g4 + j) : (16 + 4 * g4 + (j - 4));
    int k = ks * 32 + koff;
    int n = t16 * 16 + (l & 15);
    dst[e] = (f16)W[n * Kdim + k];
}

// load an A/B fragment in custom2 layout from an fp32 row pointer (32-col slice)
__device__ __forceinline__ f16x8 frag2(const float* __restrict__ p, int g4) {
    float4 a = *(const float4*)(p + 4 * g4);
    float4 b = *(const float4*)(p + 16 + 4 * g4);
    f16x8 h = {(f16)a.x, (f16)a.y, (f16)a.z, (f16)a.w,
               (f16)b.x, (f16)b.y, (f16)b.z, (f16)b.w};
    return h;
}

// ---------------------------------------------------------------------------
// Fused step: 1 wave per block, 32 rows (2 row-groups of 16). ZERO LDS,
// zero barriers: the custom2 k-mapping makes GEMM1^T / GEMM2^T outputs land
// exactly in the next GEMM's A-fragment positions, so the whole chain
// (gather -> r -> rh -> hH -> z -> softmax-mix) stays in registers.
// ---------------------------------------------------------------------------
__global__ __launch_bounds__(64) void step_kernel(
    const float* __restrict__ embP,
    float* __restrict__ embC,
    const int* __restrict__ chl,
    const f16x8* __restrict__ WrP,
    const f16x8* __restrict__ WhP,
    const f16x8* __restrict__ WzP,
    const float* __restrict__ br,
    const float* __restrict__ bh,
    const float* __restrict__ bz)
{
    const int l = threadIdx.x;
    const int l15 = l & 15;
    const int g4 = l >> 4;
    const int wbase = blockIdx.x * 32;     // M = 3125 * 32 exactly

    // ---- gather: A-fragments of [hL|hR|u] in custom2 layout, rows rg*16+l15 ----
    f16x8 aH[2][6];
#pragma unroll
    for (int rg = 0; rg < 2; ++rg) {
        int i = wbase + rg * 16 + l15;
        int iL = chl[2 * i], iR = chl[2 * i + 1];
        const float* pL = embP + (size_t)iL * 64;
        const float* pR = embP + (size_t)iR * 64;
        const float* pU = embC + (size_t)i * 64;
        aH[rg][0] = frag2(pL, g4);      aH[rg][1] = frag2(pL + 32, g4);
        aH[rg][2] = frag2(pR, g4);      aH[rg][3] = frag2(pR + 32, g4);
        aH[rg][4] = frag2(pU, g4);      aH[rg][5] = frag2(pU + 32, g4);
    }

    const f32x4 zz = {0.f, 0.f, 0.f, 0.f};

    // ---- GEMM1 (transposed): logits^T = Wr @ hhu^T ; aR = sigmoid(.) * aH ----
    // Output m-tile pair (2kr, 2kr+1) supplies exactly aR[*][kr]'s k-positions.
    f16x8 aR[2][6];
#pragma unroll
    for (int kr = 0; kr < 6; ++kr) {
        f16x8 A0[6], A1[6];
#pragma unroll
        for (int ks = 0; ks < 6; ++ks) {
            A0[ks] = WrP[((2 * kr) * 6 + ks) * 64 + l];
            A1[ks] = WrP[((2 * kr + 1) * 6 + ks) * 64 + l];
        }
        f32x4 c00 = zz, c01 = zz, c10 = zz, c11 = zz;   // c[mtLocal][rg]
#pragma unroll
        for (int ks = 0; ks < 6; ++ks) {
            c00 = MFMA(A0[ks], aH[0][ks], c00);
            c01 = MFMA(A0[ks], aH[1][ks], c01);
            c10 = MFMA(A1[ks], aH[0][ks], c10);
            c11 = MFMA(A1[ks], aH[1][ks], c11);
        }
        float4 bA = *(const float4*)(br + 32 * kr + 4 * g4);
        float4 bB = *(const float4*)(br + 32 * kr + 16 + 4 * g4);
#pragma unroll
        for (int rg = 0; rg < 2; ++rg) {
            f32x4 clo = (rg == 0) ? c00 : c01;
            f32x4 chi = (rg == 0) ? c10 : c11;
            f16x8 h = aH[rg][kr];
            float s0 = 1.f / (1.f + __expf(-(clo[0] + bA.x)));
            float s1 = 1.f / (1.f + __expf(-(clo[1] + bA.y)));
            float s2 = 1.f / (1.f + __expf(-(clo[2] + bA.z)));
            float s3 = 1.f / (1.f + __expf(-(clo[3] + bA.w)));
            float s4 = 1.f / (1.f + __expf(-(chi[0] + bB.x)));
            float s5 = 1.f / (1.f + __expf(-(chi[1] + bB.y)));
            float s6 = 1.f / (1.f + __expf(-(chi[2] + bB.z)));
            float s7 = 1.f / (1.f + __expf(-(chi[3] + bB.w)));
            f16x8 o = {(f16)(s0 * (float)h[0]), (f16)(s1 * (float)h[1]),
                       (f16)(s2 * (float)h[2]), (f16)(s3 * (float)h[3]),
                       (f16)(s4 * (float)h[4]), (f16)(s5 * (float)h[5]),
                       (f16)(s6 * (float)h[6]), (f16)(s7 * (float)h[7])};
            aR[rg][kr] = o;
        }
    }

    // ---- GEMM2, both orientations off one Wh tile stream ----
    //   hn (normal): rows=row-idx, cols=h-col  -> epilogue hH values
    //   ht (transp): rows=h-col, cols=row-idx  -> aZ fragments for GEMM3
    f32x4 hn[2][4], ht[2][4];
#pragma unroll
    for (int rg = 0; rg < 2; ++rg)
#pragma unroll
        for (int t = 0; t < 4; ++t) { hn[rg][t] = zz; ht[rg][t] = zz; }
#pragma unroll
    for (int ks = 0; ks < 6; ++ks) {
        f16x8 Wt[4];
#pragma unroll
        for (int t = 0; t < 4; ++t) Wt[t] = WhP[(t * 6 + ks) * 64 + l];
#pragma unroll
        for (int t = 0; t < 4; ++t)
#pragma unroll
            for (int rg = 0; rg < 2; ++rg) {
                hn[rg][t] = MFMA(aR[rg][ks], Wt[t], hn[rg][t]);
                ht[rg][t] = MFMA(Wt[t], aR[rg][ks], ht[rg][t]);
            }
    }
    // normal: tanh with col = 16t+l15 (kept f32 for epilogue)
    {
        float b0 = bh[l15], b1 = bh[16 + l15], b2 = bh[32 + l15], b3 = bh[48 + l15];
#pragma unroll
        for (int rg = 0; rg < 2; ++rg)
#pragma unroll
            for (int r = 0; r < 4; ++r) {
                hn[rg][0][r] = tanh_(hn[rg][0][r] + b0);
                hn[rg][1][r] = tanh_(hn[rg][1][r] + b1);
                hn[rg][2][r] = tanh_(hn[rg][2][r] + b2);
                hn[rg][3][r] = tanh_(hn[rg][3][r] + b3);
            }
    }
    // transposed: tanh with h-col = 16mt+4g4+reg -> aZ (custom2 positions)
    f16x8 aZ[2][2];
    {
        float4 bh0 = *(const float4*)(bh + 4 * g4);
        float4 bh1 = *(const float4*)(bh + 16 + 4 * g4);
        float4 bh2 = *(const float4*)(bh + 32 + 4 * g4);
        float4 bh3 = *(const float4*)(bh + 48 + 4 * g4);
#pragma unroll
        for (int rg = 0; rg < 2; ++rg) {
            f16x8 z0 = {(f16)tanh_(ht[rg][0][0] + bh0.x), (f16)tanh_(ht[rg][0][1] + bh0.y),
                        (f16)tanh_(ht[rg][0][2] + bh0.z), (f16)tanh_(ht[rg][0][3] + bh0.w),
                        (f16)tanh_(ht[rg][1][0] + bh1.x), (f16)tanh_(ht[rg][1][1] + bh1.y),
                        (f16)tanh_(ht[rg][1][2] + bh1.z), (f16)tanh_(ht[rg][1][3] + bh1.w)};
            f16x8 z1 = {(f16)tanh_(ht[rg][2][0] + bh2.x), (f16)tanh_(ht[rg][2][1] + bh2.y),
                        (f16)tanh_(ht[rg][2][2] + bh2.z), (f16)tanh_(ht[rg][2][3] + bh2.w),
                        (f16)tanh_(ht[rg][3][0] + bh3.x), (f16)tanh_(ht[rg][3][1] + bh3.y),
                        (f16)tanh_(ht[rg][3][2] + bh3.z), (f16)tanh_(ht[rg][3][3] + bh3.w)};
            aZ[rg][0] = z0;
            aZ[rg][1] = z1;
        }
    }

    // ---- preload children for epilogue rows (rg*16 + 4g4 + r) ----
    int iLr[2][4], iRr[2][4];
#pragma unroll
    for (int rg = 0; rg < 2; ++rg)
#pragma unroll
        for (int r = 0; r < 4; ++r) {
            int i = wbase + rg * 16 + 4 * g4 + r;
            iLr[rg][r] = chl[2 * i];
            iRr[rg][r] = chl[2 * i + 1];
        }

    // ---- GEMM3 (normal) + fused epilogue per 16-col group T ----
#pragma unroll
    for (int T = 0; T < 4; ++T) {
        f32x4 ac[2][4];
#pragma unroll
        for (int g = 0; g < 4; ++g) {
            int nt = g * 4 + T;
            f16x8 bb[8];
#pragma unroll
            for (int ks = 0; ks < 8; ++ks) bb[ks] = WzP[(nt * 8 + ks) * 64 + l];
#pragma unroll
            for (int rg = 0; rg < 2; ++rg) {
                f32x4 a = zz;
                a = MFMA(aZ[rg][0], bb[0], a);
                a = MFMA(aZ[rg][1], bb[1], a);
#pragma unroll
                for (int ks = 2; ks < 8; ++ks) a = MFMA(aH[rg][ks - 2], bb[ks], a);
                ac[rg][g] = a;
            }
        }
        int col = T * 16 + l15;
        float b0 = bz[col], b1 = bz[64 + col], b2 = bz[128 + col], b3 = bz[192 + col];
#pragma unroll
        for (int rg = 0; rg < 2; ++rg)
#pragma unroll
            for (int r = 0; r < 4; ++r) {
                int i = wbase + rg * 16 + 4 * g4 + r;
                float z0 = ac[rg][0][r] + b0;
                float z1 = ac[rg][1][r] + b1;
                float z2 = ac[rg][2][r] + b2;
                float z3 = ac[rg][3][r] + b3;
                float mx = fmaxf(fmaxf(z0, z1), fmaxf(z2, z3));
                float e0 = __expf(z0 - mx), e1 = __expf(z1 - mx);
                float e2 = __expf(z2 - mx), e3 = __expf(z3 - mx);
                float s = e0 + e1 + e2 + e3;
                float hHv = hn[rg][T][r];
                float hLv = embP[(size_t)iLr[rg][r] * 64 + col];
                float hRv = embP[(size_t)iRr[rg][r] * 64 + col];
                float uv  = embC[(size_t)i * 64 + col];     // read-before-write
                embC[(size_t)i * 64 + col] = (e0 * hHv + e1 * hLv + e2 * hRv + e3 * uv) / s;
            }
    }
}

// ---------------------------------------------------------------------------
extern "C" void kernel_launch(void* const* d_in, const int* in_sizes, int n_in,
                              void* d_out, int out_size, void* d_ws, size_t ws_size,
                              hipStream_t stream) {
    const float* contents = (const float*)d_in[0];
    const int*   children = (const int*)d_in[1];
    const float* Wu = (const float*)d_in[2];
    const float* bu = (const float*)d_in[3];
    const float* Wh = (const float*)d_in[4];
    const float* bh = (const float*)d_in[5];
    const float* Wz = (const float*)d_in[6];
    const float* bz = (const float*)d_in[7];
    const float* Wr = (const float*)d_in[8];
    const float* br = (const float*)d_in[9];
    float* out = (float*)d_out;
    float* ws  = (float*)d_ws;

    float* embEven = ws;                             // N*64 fp32
    f16*   pack    = (f16*)(ws + (size_t)N_DIM * H_DIM);
    const f16x8* WrP = (const f16x8*)pack;
    const f16x8* WhP = (const f16x8*)(pack + NR_PK);
    const f16x8* WzP = (const f16x8*)(pack + NR_PK + NH_PK);

    const int NPK = NR_PK + NH_PK + NZ_PK;
    prep_pack<<<(NPK + 255) / 256, 256, 0, stream>>>(Wr, Wh, Wz, pack);

    int ublocks = (N_DIM * H_DIM + 255) / 256;
    int sblocks = M_DIM / 32;    // 3125 exactly

    u_kernel<<<ublocks, 256, 0, stream>>>(contents, Wu, bu, embEven);

    for (int l = 1; l < L_DIM; ++l) {
        float* cur        = (l & 1) ? out : embEven;
        const float* prev = (l & 1) ? embEven : out;
        u_kernel<<<ublocks, 256, 0, stream>>>(contents + (size_t)l * N_DIM * F_DIM,
                                              Wu, bu, cur);
        step_kernel<<<sblocks, 64, 0, stream>>>(prev, cur,
                                                children + (size_t)(l - 1) * M_DIM * 2,
                                                WrP, WhP, WzP, br, bh, bz);
    }
}